// Round 2
// baseline (33292.014 us; speedup 1.0000x reference)
//
#include <hip/hip_runtime.h>
#include <stdint.h>

#define B_ 64
#define T_ 1024
#define I_ 128
#define H_ 512
#define O_ 64
#define RING_ 8

typedef __attribute__((ext_vector_type(8))) short bf16x8;
typedef __attribute__((ext_vector_type(4))) float f32x4;
typedef unsigned short u16;

__device__ __forceinline__ u16 f2bf(float f) {
  unsigned int u = __builtin_bit_cast(unsigned int, f);
  u += 0x7FFFu + ((u >> 16) & 1u);
  return (u16)(u >> 16);
}
__device__ __forceinline__ float bf2f(u16 h) {
  unsigned int u = ((unsigned int)h) << 16;
  return __builtin_bit_cast(float, u);
}

// ---------- fp32 -> (hi, lo) bf16 split ----------
__global__ void split_kernel(const float* __restrict__ src,
                             u16* __restrict__ hi, u16* __restrict__ lo, int n) {
  int i = blockIdx.x * 256 + threadIdx.x;
  if (i >= n) return;
  float f = src[i];
  u16 h = f2bf(f);
  hi[i] = h;
  lo[i] = f2bf(f - bf2f(h));
}

// x [B][T][I] fp32 -> xhi/xlo [T*B][I] (row r = t*B + b)
__global__ void xsplit_kernel(const float* __restrict__ x,
                              u16* __restrict__ hi, u16* __restrict__ lo) {
  int idx = blockIdx.x * 256 + threadIdx.x;  // over T*B*I
  int i = idx & (I_ - 1);
  int b = (idx >> 7) & (B_ - 1);
  int t = idx >> 13;
  float f = x[(((size_t)b << 10) | t) * I_ + i];
  u16 h = f2bf(f);
  hi[idx] = h;
  lo[idx] = f2bf(f - bf2f(h));
}

// debug sentinel: fill output with a recognizable value (ws_size in MiB)
__global__ void sentinel_kernel(float* __restrict__ out, float v, int n) {
  int i = blockIdx.x * 256 + threadIdx.x;
  if (i < n) out[i] = v;
}

// ---------- projection GEMM: xp[r][c] = sum_k A[r][k]*W[c][k] + bih[c] + bhh[c]
// A: [T*B][K] bf16 (hi, + lo if ALO) ; W: [H][K] split hi/lo ; xp fp32 [T*B][H]
template <int K, bool ALO>
__global__ __launch_bounds__(256) void proj_gemm(
    const u16* __restrict__ Ahi, const u16* __restrict__ Alo,
    const u16* __restrict__ Whi, const u16* __restrict__ Wlo,
    const float* __restrict__ bih, const float* __restrict__ bhh,
    float* __restrict__ xp) {
  __shared__ u16 lhs[2][128 * 72];  // [hi/lo][c][k], pad 72
  const int tid = threadIdx.x;
  const int w = tid >> 6, l = tid & 63;
  const int r15 = l & 15, g4 = l >> 4;
  const int Mbase = blockIdx.x * 128;
  const int Nbase = blockIdx.y * 128;
  f32x4 acc[2][8];
#pragma unroll
  for (int bt = 0; bt < 2; ++bt)
#pragma unroll
    for (int ct = 0; ct < 8; ++ct) acc[bt][ct] = (f32x4){0.f, 0.f, 0.f, 0.f};

  for (int kc = 0; kc < K; kc += 64) {
    __syncthreads();
#pragma unroll
    for (int i = 0; i < 4; ++i) {
      int e = i * 256 + tid;  // 1024 chunks of 8 elems (128c x 64k)
      int c = e >> 3, kg = (e & 7) * 8;
      *(uint4*)&lhs[0][c * 72 + kg] =
          *(const uint4*)(Whi + (size_t)(Nbase + c) * K + kc + kg);
      *(uint4*)&lhs[1][c * 72 + kg] =
          *(const uint4*)(Wlo + (size_t)(Nbase + c) * K + kc + kg);
    }
    __syncthreads();
#pragma unroll
    for (int kt = 0; kt < 2; ++kt) {
      bf16x8 ah[2], al[2];
#pragma unroll
      for (int bt = 0; bt < 2; ++bt) {
        int row = Mbase + w * 32 + bt * 16 + r15;
        int koff = kc + kt * 32 + g4 * 8;
        ah[bt] = *(const bf16x8*)(Ahi + (size_t)row * K + koff);
        if (ALO) al[bt] = *(const bf16x8*)(Alo + (size_t)row * K + koff);
      }
#pragma unroll
      for (int ct = 0; ct < 8; ++ct) {
        int lo_off = (ct * 16 + r15) * 72 + kt * 32 + g4 * 8;
        bf16x8 bh = *(const bf16x8*)&lhs[0][lo_off];
        bf16x8 bl = *(const bf16x8*)&lhs[1][lo_off];
#pragma unroll
        for (int bt = 0; bt < 2; ++bt) {
          acc[bt][ct] = __builtin_amdgcn_mfma_f32_16x16x32_bf16(ah[bt], bh, acc[bt][ct], 0, 0, 0);
          acc[bt][ct] = __builtin_amdgcn_mfma_f32_16x16x32_bf16(ah[bt], bl, acc[bt][ct], 0, 0, 0);
          if (ALO)
            acc[bt][ct] = __builtin_amdgcn_mfma_f32_16x16x32_bf16(al[bt], bh, acc[bt][ct], 0, 0, 0);
        }
      }
    }
  }
#pragma unroll
  for (int ct = 0; ct < 8; ++ct) {
    int col = Nbase + ct * 16 + r15;
    float bc = bih[col] + bhh[col];
#pragma unroll
    for (int bt = 0; bt < 2; ++bt) {
#pragma unroll
      for (int j = 0; j < 4; ++j) {
        int row = Mbase + w * 32 + bt * 16 + g4 * 4 + j;
        xp[(size_t)row * H_ + col] = acc[bt][ct][j] + bc;
      }
    }
  }
}

// ---------- recurrent scan for one layer ----------
// grid = 128 WGs (bg = bx>>5 in [0,4): 16 batch rows ; cg = bx&31: 16 cols), 64 thr.
// y_hi [T][B][H] bf16: slot t = ys[t] = h_{t+1} (hi part).
// ring [RING_][B][H] bf16: slot s&7 = lo(h_s) for s>=1. h0 via h0hi/h0lo.
// flags per bg: flg[t] counts producers of h_t (32 when ready).
__global__ __launch_bounds__(64) void scan_kernel(
    const u16* __restrict__ whh_hi, const u16* __restrict__ whh_lo,
    const float* __restrict__ xp,
    const u16* __restrict__ h0hi, const u16* __restrict__ h0lo,
    u16* __restrict__ yhi, u16* __restrict__ ring,
    float* __restrict__ hn_out, unsigned int* __restrict__ flags) {
  __shared__ u16 lw[2][16 * 520];  // W slice [hi/lo][16 cols][512k], pad 520
  const int l = threadIdx.x;
  const int cg = blockIdx.x & 31, bg = blockIdx.x >> 5;
  const int r15 = l & 15, g4 = l >> 4;
#pragma unroll
  for (int i = 0; i < 16; ++i) {
    int e = i * 64 + l;  // 1024 chunks of 8 (16c x 64kg)
    int c = e >> 6, kg = (e & 63) * 8;
    *(uint4*)&lw[0][c * 520 + kg] = *(const uint4*)(whh_hi + (size_t)(cg * 16 + c) * H_ + kg);
    *(uint4*)&lw[1][c * 520 + kg] = *(const uint4*)(whh_lo + (size_t)(cg * 16 + c) * H_ + kg);
  }
  __syncthreads();
  unsigned int* flg = flags + bg * (T_ + 1);
  const int browA = bg * 16 + r15;     // A-fragment row (m = lane&15)
  const int brow0 = bg * 16 + g4 * 4;  // C rows base (row = (lane>>4)*4 + j)
  const int col = cg * 16 + r15;       // output col (n = lane&15)
  const u16* lwp_hi = &lw[0][r15 * 520 + g4 * 8];
  const u16* lwp_lo = &lw[1][r15 * 520 + g4 * 8];
  for (int t = 0; t < T_; ++t) {
    // xp prefetch — independent of the flag, hides latency under the spin
    f32x4 acc;
#pragma unroll
    for (int j = 0; j < 4; ++j)
      acc[j] = xp[(size_t)(t * B_ + brow0 + j) * H_ + col];
    if (t > 0) {
      while (__hip_atomic_load(&flg[t], __ATOMIC_ACQUIRE, __HIP_MEMORY_SCOPE_AGENT) < 32u)
        __builtin_amdgcn_s_sleep(1);
    }
    const u16* hb_hi =
        (t == 0 ? h0hi : yhi + (size_t)(t - 1) * B_ * H_) + (size_t)browA * H_ + g4 * 8;
    const u16* hb_lo =
        (t == 0 ? h0lo : ring + (size_t)(t & (RING_ - 1)) * B_ * H_) + (size_t)browA * H_ + g4 * 8;
    bf16x8 ah[16], al[16];
#pragma unroll
    for (int kt = 0; kt < 16; ++kt) {
      ah[kt] = *(const bf16x8*)(hb_hi + kt * 32);
      al[kt] = *(const bf16x8*)(hb_lo + kt * 32);
    }
#pragma unroll
    for (int kt = 0; kt < 16; ++kt) {
      bf16x8 bh = *(const bf16x8*)(lwp_hi + kt * 32);
      bf16x8 bl = *(const bf16x8*)(lwp_lo + kt * 32);
      acc = __builtin_amdgcn_mfma_f32_16x16x32_bf16(ah[kt], bh, acc, 0, 0, 0);
      acc = __builtin_amdgcn_mfma_f32_16x16x32_bf16(al[kt], bh, acc, 0, 0, 0);
      acc = __builtin_amdgcn_mfma_f32_16x16x32_bf16(ah[kt], bl, acc, 0, 0, 0);
    }
#pragma unroll
    for (int j = 0; j < 4; ++j) {
      float v = tanhf(acc[j]);
      int row = brow0 + j;
      u16 h = f2bf(v);
      yhi[((size_t)t * B_ + row) * H_ + col] = h;
      ring[((size_t)((t + 1) & (RING_ - 1)) * B_ + row) * H_ + col] = f2bf(v - bf2f(h));
      if (t == T_ - 1) hn_out[row * H_ + col] = v;
    }
    __threadfence();
    if (l == 0)
      __hip_atomic_fetch_add(&flg[t + 1], 1u, __ATOMIC_RELEASE, __HIP_MEMORY_SCOPE_AGENT);
  }
}

// ---------- final FC + sigmoid ----------
__global__ __launch_bounds__(64) void fc_kernel(const float* __restrict__ hn2,
                                                const float* __restrict__ wfc,
                                                const float* __restrict__ bfc,
                                                float* __restrict__ out) {
  int b = blockIdx.x, o = threadIdx.x;
  __shared__ float hs[H_];
  for (int i = o; i < H_; i += 64) hs[i] = hn2[(size_t)b * H_ + i];
  __syncthreads();
  float acc = bfc[o];
#pragma unroll 4
  for (int k = 0; k < H_; k += 4) {
    float4 wv = *(const float4*)(wfc + (size_t)o * H_ + k);
    acc += hs[k] * wv.x + hs[k + 1] * wv.y + hs[k + 2] * wv.z + hs[k + 3] * wv.w;
  }
  out[b * O_ + o] = 1.f / (1.f + expf(-acc));
}

extern "C" void kernel_launch(void* const* d_in, const int* in_sizes, int n_in,
                              void* d_out, int out_size, void* d_ws, size_t ws_size,
                              hipStream_t stream) {
  (void)in_sizes; (void)n_in; (void)out_size;
  const float* x = (const float*)d_in[0];
  const float* h0 = (const float*)d_in[1];
  const float* w_ih[3] = {(const float*)d_in[2], (const float*)d_in[6], (const float*)d_in[10]};
  const float* w_hh[3] = {(const float*)d_in[3], (const float*)d_in[7], (const float*)d_in[11]};
  const float* b_ih[3] = {(const float*)d_in[4], (const float*)d_in[8], (const float*)d_in[12]};
  const float* b_hh[3] = {(const float*)d_in[5], (const float*)d_in[9], (const float*)d_in[13]};
  const float* w_fc = (const float*)d_in[14];
  const float* b_fc = (const float*)d_in[15];
  float* out = (float*)d_out;
  float* hn = out + B_ * O_;

  char* p = (char*)d_ws;
  auto carve = [&](size_t bytes) {
    char* r = p;
    p += (bytes + 255) & ~(size_t)255;
    return r;
  };
  float* xp = (float*)carve((size_t)T_ * B_ * H_ * 4);            // 128 MiB
  u16* yhi = (u16*)carve((size_t)T_ * B_ * H_ * 2);               // 64 MiB
  u16* ring = (u16*)carve((size_t)RING_ * B_ * H_ * 2);           // 0.5 MiB
  u16* h0hi = (u16*)carve((size_t)B_ * H_ * 2);
  u16* h0lo = (u16*)carve((size_t)B_ * H_ * 2);
  u16 *whhh[3], *whhl[3], *wihh[3], *wihl[3];
  for (int l = 0; l < 3; ++l) {
    whhh[l] = (u16*)carve((size_t)H_ * H_ * 2);
    whhl[l] = (u16*)carve((size_t)H_ * H_ * 2);
    int kin = (l == 0) ? I_ : H_;
    wihh[l] = (u16*)carve((size_t)H_ * kin * 2);
    wihl[l] = (u16*)carve((size_t)H_ * kin * 2);
  }
  unsigned int* flags = (unsigned int*)carve((size_t)3 * 4 * (T_ + 1) * 4);
  size_t required = (size_t)(p - (char*)d_ws);
  if (required > ws_size) {
    // report ws_size (MiB) through the output so the failure is diagnosable
    int n = B_ * O_ + 3 * B_ * H_;
    sentinel_kernel<<<(n + 255) / 256, 256, 0, stream>>>(out, (float)(ws_size >> 20), n);
    return;
  }
  // x-split aliases the y_hi region (dead before scan-0 first writes y_hi)
  u16* xhi = yhi;
  u16* xlo = yhi + (size_t)T_ * B_ * I_;

  hipMemsetAsync(flags, 0, (size_t)3 * 4 * (T_ + 1) * 4, stream);

  for (int l = 0; l < 3; ++l) {
    split_kernel<<<H_ * H_ / 256, 256, 0, stream>>>(w_hh[l], whhh[l], whhl[l], H_ * H_);
    int kin = (l == 0) ? I_ : H_;
    split_kernel<<<H_ * kin / 256, 256, 0, stream>>>(w_ih[l], wihh[l], wihl[l], H_ * kin);
  }
  xsplit_kernel<<<T_ * B_ * I_ / 256, 256, 0, stream>>>(x, xhi, xlo);

  for (int l = 0; l < 3; ++l) {
    split_kernel<<<B_ * H_ / 256, 256, 0, stream>>>(h0 + (size_t)l * B_ * H_, h0hi, h0lo, B_ * H_);
    if (l == 0)
      proj_gemm<I_, true><<<dim3(T_ * B_ / 128, H_ / 128), 256, 0, stream>>>(
          xhi, xlo, wihh[0], wihl[0], b_ih[0], b_hh[0], xp);
    else
      proj_gemm<H_, false><<<dim3(T_ * B_ / 128, H_ / 128), 256, 0, stream>>>(
          yhi, yhi, wihh[l], wihl[l], b_ih[l], b_hh[l], xp);
    scan_kernel<<<128, 64, 0, stream>>>(whhh[l], whhl[l], xp, h0hi, h0lo, yhi, ring,
                                        hn + (size_t)l * B_ * H_,
                                        flags + (size_t)l * 4 * (T_ + 1));
  }
  fc_kernel<<<B_, O_, 0, stream>>>(hn + 2 * (size_t)B_ * H_, w_fc, b_fc, out);
}